// Round 16
// baseline (64.418 us; speedup 1.0000x reference)
//
#include <hip/hip_runtime.h>
#include <stdint.h>

#define S_TOT 4096
#define CH 128
#define NH 4
#define DH 32

typedef __attribute__((ext_vector_type(4))) float f32x4;
typedef __attribute__((ext_vector_type(8))) short s16x8;

__device__ __forceinline__ unsigned short f2bf(float f){
  union { float f; unsigned u; } v; v.f = f;
  unsigned r = v.u + 0x7fffu + ((v.u >> 16) & 1u);
  return (unsigned short)(r >> 16);
}
__device__ __forceinline__ unsigned pk2(float a, float b){
  return (unsigned)f2bf(a) | ((unsigned)f2bf(b) << 16);
}
__device__ __forceinline__ unsigned cvtpk(float a, float b){
  unsigned r;
  asm("v_cvt_pk_bf16_f32 %0, %1, %2" : "=v"(r) : "v"(a), "v"(b));
  return r;
}
__device__ __forceinline__ float bf2f(unsigned short u){
  union { unsigned u; float f; } v; v.u = ((unsigned)u) << 16;
  return v.f;
}
// async global->LDS, 16B per lane; LDS dst is wave-uniform base + lane*16 (HW), global src per-lane.
__device__ __forceinline__ void g2l16(const unsigned short* g, unsigned short* l){
  __builtin_amdgcn_global_load_lds(
      (__attribute__((address_space(1))) void*)const_cast<unsigned short*>(g),
      (__attribute__((address_space(3))) void*)l, 16, 0, 0);
}

// ---------------- kernel 1: merged weight-prep + groupnorm stats ----------------
__global__ void k_pre(const float* __restrict__ x, float* __restrict__ stats,
                      const float* __restrict__ qkvw, const float* __restrict__ projw,
                      unsigned short* __restrict__ wq, unsigned short* __restrict__ wp){
  if (blockIdx.x >= 64){
    int i = (blockIdx.x - 64) * 256 + threadIdx.x;
    if (i < 384*128) wq[i] = f2bf(qkvw[i]);
    int j = i - 384*128;
    if (j >= 0 && j < 128*128) wp[j] = f2bf(projw[j]);
    return;
  }
  int bg = blockIdx.x;
  const float4* p = (const float4*)(x + (size_t)bg * 16384);
  float s = 0.f, ss = 0.f;
  #pragma unroll
  for (int i = 0; i < 16; ++i){
    float4 v = p[threadIdx.x + i*256];
    s  += v.x + v.y + v.z + v.w;
    ss += v.x*v.x + v.y*v.y + v.z*v.z + v.w*v.w;
  }
  #pragma unroll
  for (int m = 1; m < 64; m <<= 1){ s += __shfl_xor(s, m); ss += __shfl_xor(ss, m); }
  __shared__ float red[8];
  int wid = threadIdx.x >> 6;
  if ((threadIdx.x & 63) == 0){ red[wid*2] = s; red[wid*2+1] = ss; }
  __syncthreads();
  if (threadIdx.x == 0){
    float S = red[0]+red[2]+red[4]+red[6], SS = red[1]+red[3]+red[5]+red[7];
    float mean = S * (1.f/16384.f);
    float var  = SS * (1.f/16384.f) - mean*mean;
    stats[bg*2]   = mean;
    stats[bg*2+1] = rsqrtf(var + 1e-5f);
  }
}

// ---------------- kernel 3: apply GN + transpose to hT [B][S][C] bf16 ----------------
__global__ void k_gnapply(const float* __restrict__ x, const float* __restrict__ stats,
                          const float* __restrict__ nw, const float* __restrict__ nb,
                          unsigned short* __restrict__ hT){
  __shared__ float lds[64*129];
  int b  = blockIdx.x >> 6;
  int s0 = (blockIdx.x & 63) * 64;
  int sid = threadIdx.x & 63, cg = threadIdx.x >> 6;
  #pragma unroll 4
  for (int c4 = 0; c4 < 32; ++c4){
    int c = c4*4 + cg;
    float mean = stats[(b*32 + c4)*2], rstd = stats[(b*32 + c4)*2 + 1];
    float v = x[((size_t)(b*CH + c))*S_TOT + s0 + sid];
    v = (v - mean) * rstd * nw[c] + nb[c];
    lds[sid*129 + c] = v;
  }
  __syncthreads();
  int row = threadIdx.x >> 2, q = threadIdx.x & 3, c0 = q*32;
  unsigned short* dst = hT + ((size_t)(b*S_TOT) + s0 + row) * CH + c0;
  const float* src = lds + row*129 + c0;
  #pragma unroll
  for (int cc = 0; cc < 4; ++cc){
    uint4 w;
    w.x = pk2(src[cc*8+0], src[cc*8+1]);
    w.y = pk2(src[cc*8+2], src[cc*8+3]);
    w.z = pk2(src[cc*8+4], src[cc*8+5]);
    w.w = pk2(src[cc*8+6], src[cc*8+7]);
    *(uint4*)(dst + cc*8) = w;
  }
}

// ---------------- kernel 4: QKV GEMM (bf16 MFMA) — r9-proven layout ----------------
// q scaled by scale*log2e, stored [b][h][s][d].
// K and V interleaved per 32-key tile: kv[bh][tile][0..1023]   = K rows (s&31)*32 + d
//                                      kv[bh][tile][1024..2047]= V slots d*32 + (hi2*8+j2)
__global__ void k_qkv(const unsigned short* __restrict__ hT, const unsigned short* __restrict__ wq,
                      const float* __restrict__ qkvb,
                      unsigned short* __restrict__ qT, unsigned short* __restrict__ kv){
  const float SC = 0.17677669529663687f * 1.4426950408889634f; // (1/sqrt(32)) * log2(e)
  int lane = threadIdx.x & 63, wid = threadIdx.x >> 6;
  int lo = lane & 15, hi = lane >> 4;
  int b  = blockIdx.z;
  int o0 = blockIdx.y * 64 + wid * 16;
  int sb = blockIdx.x * 64;
  s16x8 af[4];
  #pragma unroll
  for (int kk = 0; kk < 4; ++kk)
    af[kk] = *(const s16x8*)(wq + (size_t)(o0+lo)*CH + kk*32 + hi*8);
  #pragma unroll
  for (int st = 0; st < 4; ++st){
    int s0 = sb + st*16;
    const unsigned short* hrow = hT + ((size_t)(b*S_TOT) + s0 + lo) * CH + hi*8;
    f32x4 acc = {0.f,0.f,0.f,0.f};
    #pragma unroll
    for (int kk = 0; kk < 4; ++kk){
      s16x8 bfr = *(const s16x8*)(hrow + kk*32);
      acc = __builtin_amdgcn_mfma_f32_16x16x32_bf16(af[kk], bfr, acc, 0, 0, 0);
    }
    int s = s0 + lo;
    #pragma unroll
    for (int r = 0; r < 4; ++r){
      int o = o0 + hi*4 + r;
      float val = acc[r] + qkvb[o];
      if (o < 128){
        int h = o >> 5, d = o & 31;
        qT[(((size_t)(b*NH + h))*S_TOT + s)*DH + d] = f2bf(val * SC);
      } else if (o < 256){
        int o2 = o - 128, h = o2 >> 5, d = o2 & 31;
        kv[(((size_t)(b*NH + h)*128 + (s >> 5)) << 11) + ((s & 31) << 5) + d] = f2bf(val);
      } else {
        int o3 = o - 256, h = o3 >> 5, d = o3 & 31;
        int pos = s & 31;
        int hi2 = (pos & 15) >> 2;
        int j2  = (pos & 3) + ((pos & 16) ? 4 : 0);
        kv[(((size_t)(b*NH + h)*128 + (s >> 5)) << 11) + 1024 + (d << 5) + hi2*8 + j2] = f2bf(val);
      }
    }
  }
}

// ---------------- kernel 5: flash attention, split-KV=8, 8-wave blocks, 4-tile LDS groups ----------------
// 512 threads = 8 waves x 32 queries; groups of 4 tiles (16KB), double-buffered (32KB LDS).
// Each wave stages 2KB (two g2l16) of the shared group; one __syncthreads per group.
__global__ void __launch_bounds__(512) k_attn(const unsigned short* __restrict__ qT,
                                              const unsigned short* __restrict__ kv,
                                              unsigned short* __restrict__ po,
                                              float* __restrict__ ls){
  __shared__ __align__(16) unsigned short smem[16384];  // 32 KB: 2 bufs x 4 tiles x 2048
  int lane = threadIdx.x & 63;
  int wid = threadIdx.x >> 6;          // 0..7
  int lo = lane & 15, hi = lane >> 4;
  int bh = blockIdx.x & 7;             // x%8 == head -> one head per XCD
  int sp = blockIdx.x >> 3;            // split 0..7
  int sw = blockIdx.y * 256 + wid * 32;
  int tb = sp * 16;                    // 16 tiles of 32 keys = 512 keys per split
  const unsigned short* qh = qT + (size_t)bh * S_TOT * DH;
  const unsigned short* kvbase = kv + (((size_t)bh*128 + tb) << 11);

  s16x8 qf0 = *(const s16x8*)(qh + (size_t)(sw + lo)*DH + hi*8);
  s16x8 qf1 = *(const s16x8*)(qh + (size_t)(sw + 16 + lo)*DH + hi*8);
  const f32x4 z = {0.f,0.f,0.f,0.f};
  f32x4 acc00 = z, acc01 = z, acc10 = z, acc11 = z, accL0 = z, accL1 = z;
  s16x8 onesf;
  #pragma unroll
  for (int i = 0; i < 8; ++i) onesf[i] = (short)0x3F80; // bf16 1.0

  auto compute = [&](const s16x8& kf0, const s16x8& kf1, const s16x8& vf0, const s16x8& vf1){
    __builtin_amdgcn_s_setprio(1);
    f32x4 p0 = __builtin_amdgcn_mfma_f32_16x16x32_bf16(kf0, qf0, z, 0, 0, 0);
    f32x4 p1 = __builtin_amdgcn_mfma_f32_16x16x32_bf16(kf1, qf0, z, 0, 0, 0);
    f32x4 r0 = __builtin_amdgcn_mfma_f32_16x16x32_bf16(kf0, qf1, z, 0, 0, 0);
    f32x4 r1 = __builtin_amdgcn_mfma_f32_16x16x32_bf16(kf1, qf1, z, 0, 0, 0);
    #pragma unroll
    for (int r = 0; r < 4; ++r){
      p0[r] = __builtin_amdgcn_exp2f(p0[r]);
      p1[r] = __builtin_amdgcn_exp2f(p1[r]);
      r0[r] = __builtin_amdgcn_exp2f(r0[r]);
      r1[r] = __builtin_amdgcn_exp2f(r1[r]);
    }
    union { unsigned u[4]; s16x8 v; } pa0, pa1;
    pa0.u[0] = cvtpk(p0[0],p0[1]); pa0.u[1] = cvtpk(p0[2],p0[3]);
    pa0.u[2] = cvtpk(p1[0],p1[1]); pa0.u[3] = cvtpk(p1[2],p1[3]);
    pa1.u[0] = cvtpk(r0[0],r0[1]); pa1.u[1] = cvtpk(r0[2],r0[3]);
    pa1.u[2] = cvtpk(r1[0],r1[1]); pa1.u[3] = cvtpk(r1[2],r1[3]);
    acc00 = __builtin_amdgcn_mfma_f32_16x16x32_bf16(pa0.v, vf0, acc00, 0, 0, 0);
    acc01 = __builtin_amdgcn_mfma_f32_16x16x32_bf16(pa0.v, vf1, acc01, 0, 0, 0);
    acc10 = __builtin_amdgcn_mfma_f32_16x16x32_bf16(pa1.v, vf0, acc10, 0, 0, 0);
    acc11 = __builtin_amdgcn_mfma_f32_16x16x32_bf16(pa1.v, vf1, acc11, 0, 0, 0);
    accL0 = __builtin_amdgcn_mfma_f32_16x16x32_bf16(pa0.v, onesf, accL0, 0, 0, 0);
    accL1 = __builtin_amdgcn_mfma_f32_16x16x32_bf16(pa1.v, onesf, accL1, 0, 0, 0);
    __builtin_amdgcn_s_setprio(0);
  };

  // prologue: async-stage group 0 (4 tiles = 16KB) into buf 0; each wave 2KB via two g2l16
  g2l16(kvbase + wid*1024 + lane*8,       smem + wid*1024);
  g2l16(kvbase + wid*1024 + 512 + lane*8, smem + wid*1024 + 512);
  __syncthreads();

  int buf = 0;
  for (int grp = 0; grp < 4; ++grp){
    if (grp < 3){                              // stage next 4-tile group
      const unsigned short* g = kvbase + (grp + 1)*8192 + wid*1024 + lane*8;
      unsigned short* l = smem + (buf^1)*8192 + wid*1024;
      g2l16(g, l);
      g2l16(g + 512, l + 512);
    }
    const unsigned short* lb = smem + buf*8192 + (lo << 5) + hi*8;
    #pragma unroll
    for (int t = 0; t < 4; ++t){
      const unsigned short* tl = lb + t*2048;
      s16x8 kf0 = *(const s16x8*)(tl);
      s16x8 kf1 = *(const s16x8*)(tl + 512);
      s16x8 vf0 = *(const s16x8*)(tl + 1024);
      s16x8 vf1 = *(const s16x8*)(tl + 1536);
      compute(kf0, kf1, vf0, vf1);
    }
    __syncthreads();                           // drains vmcnt(0): staged group visible
    buf ^= 1;
  }

  unsigned short* pob = po + (size_t)(bh*8 + sp) * S_TOT * DH;
  float* lsb = ls + (size_t)(bh*8 + sp) * S_TOT;
  #pragma unroll
  for (int r = 0; r < 4; ++r){
    int s0r = sw + hi*4 + r;
    pob[(size_t)s0r*DH + lo]      = f2bf(acc00[r]);
    pob[(size_t)s0r*DH + lo + 16] = f2bf(acc01[r]);
    int s1r = sw + 16 + hi*4 + r;
    pob[(size_t)s1r*DH + lo]      = f2bf(acc10[r]);
    pob[(size_t)s1r*DH + lo + 16] = f2bf(acc11[r]);
  }
  if (lo == 0){
    #pragma unroll
    for (int r = 0; r < 4; ++r){
      lsb[sw + hi*4 + r]      = accL0[r];
      lsb[sw + 16 + hi*4 + r] = accL1[r];
    }
  }
}

// ---------------- kernel 5b: combine split-KV partials (bf16) -> aoT bf16 ----------------
__global__ void k_comb(const unsigned short* __restrict__ po, const float* __restrict__ ls,
                       unsigned short* __restrict__ aoT){
  int t = blockIdx.x * 256 + threadIdx.x;    // 262144 threads, 4 outputs each
  int d4 = (t & 7) * 4;
  int s  = (t >> 3) & 4095;
  int bh = t >> 15;
  float l = 0.f;
  float4 v = {0.f,0.f,0.f,0.f};
  #pragma unroll
  for (int sp = 0; sp < 8; ++sp){
    size_t base = (size_t)(bh*8 + sp) * S_TOT + s;
    l += ls[base];
    ushort4 pv = *(const ushort4*)(po + base*DH + d4);
    v.x += bf2f(pv.x); v.y += bf2f(pv.y); v.z += bf2f(pv.z); v.w += bf2f(pv.w);
  }
  float inv = 1.f / l;
  ushort4 o;
  o.x = f2bf(v.x * inv); o.y = f2bf(v.y * inv);
  o.z = f2bf(v.z * inv); o.w = f2bf(v.w * inv);
  *(ushort4*)(aoT + ((size_t)(bh*4096 + s))*DH + d4) = o;
}

// ---------------- kernel 6: proj GEMM + bias + residual ----------------
__global__ void k_proj(const unsigned short* __restrict__ aoT, const unsigned short* __restrict__ wp,
                       const float* __restrict__ pb, const float* __restrict__ x,
                       float* __restrict__ out){
  int lane = threadIdx.x & 63, wid = threadIdx.x >> 6;
  int lo = lane & 15, hi = lane >> 4;
  int b  = blockIdx.z;
  int o0 = blockIdx.y * 64 + wid * 16;
  int sb = blockIdx.x * 64;
  s16x8 af[4];
  #pragma unroll
  for (int kk = 0; kk < 4; ++kk)
    af[kk] = *(const s16x8*)(wp + (size_t)(o0+lo)*CH + kk*32 + hi*8);
  #pragma unroll
  for (int st = 0; st < 4; ++st){
    int s0 = sb + st*16;
    f32x4 acc = {0.f,0.f,0.f,0.f};
    #pragma unroll
    for (int kk = 0; kk < 4; ++kk){
      s16x8 bfr = *(const s16x8*)(aoT + (((size_t)(b*NH + kk))*S_TOT + s0 + lo)*DH + hi*8);
      acc = __builtin_amdgcn_mfma_f32_16x16x32_bf16(af[kk], bfr, acc, 0, 0, 0);
    }
    #pragma unroll
    for (int r = 0; r < 4; ++r){
      int o = o0 + hi*4 + r;
      size_t idx = ((size_t)(b*CH + o))*S_TOT + s0 + lo;
      out[idx] = acc[r] + pb[o] + x[idx];
    }
  }
}

extern "C" void kernel_launch(void* const* d_in, const int* in_sizes, int n_in,
                              void* d_out, int out_size, void* d_ws, size_t ws_size,
                              hipStream_t stream){
  const float* x     = (const float*)d_in[0];
  const float* nw    = (const float*)d_in[1];
  const float* nb    = (const float*)d_in[2];
  const float* qkvw  = (const float*)d_in[3];
  const float* qkvb  = (const float*)d_in[4];
  const float* projw = (const float*)d_in[5];
  const float* projb = (const float*)d_in[6];
  float* out = (float*)d_out;
  char* ws = (char*)d_ws;
  const size_t MB = 1048576;
  unsigned short* qT  = (unsigned short*)(ws);            // 2MB
  unsigned short* kv  = (unsigned short*)(ws + 2*MB);     // 4MB (K+V interleaved per tile)
  unsigned short* aoT = (unsigned short*)(ws + 6*MB);     // 2MB
  unsigned short* wq  = (unsigned short*)(ws + 8*MB);           // 96KB
  unsigned short* wp  = (unsigned short*)(ws + 8*MB + 131072);  // 32KB
  float* stats        = (float*)(ws + 8*MB + 196608);           // 512B
  float* ls           = (float*)(ws + 8*MB + 262144);           // 1MB (64*4096*4B)
  unsigned short* hT  = (unsigned short*)(ws + 10*MB);    // 2MB
  unsigned short* po  = (unsigned short*)(ws + 12*MB);    // 16MB bf16 partials (total 28MB)

  hipLaunchKernelGGL(k_pre,     dim3(320),      dim3(256), 0, stream, x, stats, qkvw, projw, wq, wp);
  hipLaunchKernelGGL(k_gnapply, dim3(128),      dim3(256), 0, stream, x, stats, nw, nb, hT);
  hipLaunchKernelGGL(k_qkv,     dim3(64, 6, 2), dim3(256), 0, stream, hT, wq, qkvb, qT, kv);
  hipLaunchKernelGGL(k_attn,    dim3(64, 16),   dim3(512), 0, stream, qT, kv, po, ls);
  hipLaunchKernelGGL(k_comb,    dim3(1024),     dim3(256), 0, stream, po, ls, aoT);
  hipLaunchKernelGGL(k_proj,    dim3(64, 2, 2), dim3(256), 0, stream, aoT, wp, projb, x, out);
}

// Round 17
// 58.033 us; speedup vs baseline: 1.1100x; 1.1100x over previous
//
#include <hip/hip_runtime.h>
#include <stdint.h>

#define S_TOT 4096
#define CH 128
#define NH 4
#define DH 32

typedef __attribute__((ext_vector_type(4))) float f32x4;
typedef __attribute__((ext_vector_type(8))) short s16x8;

__device__ __forceinline__ unsigned short f2bf(float f){
  union { float f; unsigned u; } v; v.f = f;
  unsigned r = v.u + 0x7fffu + ((v.u >> 16) & 1u);
  return (unsigned short)(r >> 16);
}
__device__ __forceinline__ unsigned pk2(float a, float b){
  return (unsigned)f2bf(a) | ((unsigned)f2bf(b) << 16);
}
__device__ __forceinline__ unsigned cvtpk(float a, float b){
  unsigned r;
  asm("v_cvt_pk_bf16_f32 %0, %1, %2" : "=v"(r) : "v"(a), "v"(b));
  return r;
}
__device__ __forceinline__ float bf2f(unsigned short u){
  union { unsigned u; float f; } v; v.u = ((unsigned)u) << 16;
  return v.f;
}
// async global->LDS, 16B per lane; LDS dst is wave-uniform base + lane*16 (HW), global src per-lane.
__device__ __forceinline__ void g2l16(const unsigned short* g, unsigned short* l){
  __builtin_amdgcn_global_load_lds(
      (__attribute__((address_space(1))) void*)const_cast<unsigned short*>(g),
      (__attribute__((address_space(3))) void*)l, 16, 0, 0);
}

// ---------------- kernel 1: merged weight-prep + groupnorm stats ----------------
__global__ void k_pre(const float* __restrict__ x, float* __restrict__ stats,
                      const float* __restrict__ qkvw, const float* __restrict__ projw,
                      unsigned short* __restrict__ wq, unsigned short* __restrict__ wp){
  if (blockIdx.x >= 64){
    int i = (blockIdx.x - 64) * 256 + threadIdx.x;
    if (i < 384*128) wq[i] = f2bf(qkvw[i]);
    int j = i - 384*128;
    if (j >= 0 && j < 128*128) wp[j] = f2bf(projw[j]);
    return;
  }
  int bg = blockIdx.x;
  const float4* p = (const float4*)(x + (size_t)bg * 16384);
  float s = 0.f, ss = 0.f;
  #pragma unroll
  for (int i = 0; i < 16; ++i){
    float4 v = p[threadIdx.x + i*256];
    s  += v.x + v.y + v.z + v.w;
    ss += v.x*v.x + v.y*v.y + v.z*v.z + v.w*v.w;
  }
  #pragma unroll
  for (int m = 1; m < 64; m <<= 1){ s += __shfl_xor(s, m); ss += __shfl_xor(ss, m); }
  __shared__ float red[8];
  int wid = threadIdx.x >> 6;
  if ((threadIdx.x & 63) == 0){ red[wid*2] = s; red[wid*2+1] = ss; }
  __syncthreads();
  if (threadIdx.x == 0){
    float S = red[0]+red[2]+red[4]+red[6], SS = red[1]+red[3]+red[5]+red[7];
    float mean = S * (1.f/16384.f);
    float var  = SS * (1.f/16384.f) - mean*mean;
    stats[bg*2]   = mean;
    stats[bg*2+1] = rsqrtf(var + 1e-5f);
  }
}

// ---------------- kernel 3: apply GN + transpose to hT [B][S][C] bf16 (32-s tiles, 256 blocks) ----------------
__global__ void k_gnapply(const float* __restrict__ x, const float* __restrict__ stats,
                          const float* __restrict__ nw, const float* __restrict__ nb,
                          unsigned short* __restrict__ hT){
  __shared__ float lds[32*129];
  int b  = blockIdx.x >> 7;
  int s0 = (blockIdx.x & 127) * 32;
  int sid = threadIdx.x & 31, cg = threadIdx.x >> 5;   // cg 0..7
  #pragma unroll 4
  for (int c4 = 0; c4 < 16; ++c4){
    int c = c4*8 + cg;
    float mean = stats[(b*32 + (c >> 2))*2], rstd = stats[(b*32 + (c >> 2))*2 + 1];
    float v = x[((size_t)(b*CH + c))*S_TOT + s0 + sid];
    v = (v - mean) * rstd * nw[c] + nb[c];
    lds[sid*129 + c] = v;
  }
  __syncthreads();
  int row = threadIdx.x >> 3, q = threadIdx.x & 7, c0 = q*16;
  unsigned short* dst = hT + ((size_t)(b*S_TOT) + s0 + row) * CH + c0;
  const float* src = lds + row*129 + c0;
  #pragma unroll
  for (int cc = 0; cc < 2; ++cc){
    uint4 w;
    w.x = pk2(src[cc*8+0], src[cc*8+1]);
    w.y = pk2(src[cc*8+2], src[cc*8+3]);
    w.z = pk2(src[cc*8+4], src[cc*8+5]);
    w.w = pk2(src[cc*8+6], src[cc*8+7]);
    *(uint4*)(dst + cc*8) = w;
  }
}

// ---------------- kernel 4: QKV GEMM (bf16 MFMA) — r9-proven layout ----------------
// q scaled by scale*log2e, stored [b][h][s][d].
// K and V interleaved per 32-key tile: kv[bh][tile][0..1023]   = K rows (s&31)*32 + d
//                                      kv[bh][tile][1024..2047]= V slots d*32 + (hi2*8+j2)
__global__ void k_qkv(const unsigned short* __restrict__ hT, const unsigned short* __restrict__ wq,
                      const float* __restrict__ qkvb,
                      unsigned short* __restrict__ qT, unsigned short* __restrict__ kv){
  const float SC = 0.17677669529663687f * 1.4426950408889634f; // (1/sqrt(32)) * log2(e)
  int lane = threadIdx.x & 63, wid = threadIdx.x >> 6;
  int lo = lane & 15, hi = lane >> 4;
  int b  = blockIdx.z;
  int o0 = blockIdx.y * 64 + wid * 16;
  int sb = blockIdx.x * 64;
  s16x8 af[4];
  #pragma unroll
  for (int kk = 0; kk < 4; ++kk)
    af[kk] = *(const s16x8*)(wq + (size_t)(o0+lo)*CH + kk*32 + hi*8);
  #pragma unroll
  for (int st = 0; st < 4; ++st){
    int s0 = sb + st*16;
    const unsigned short* hrow = hT + ((size_t)(b*S_TOT) + s0 + lo) * CH + hi*8;
    f32x4 acc = {0.f,0.f,0.f,0.f};
    #pragma unroll
    for (int kk = 0; kk < 4; ++kk){
      s16x8 bfr = *(const s16x8*)(hrow + kk*32);
      acc = __builtin_amdgcn_mfma_f32_16x16x32_bf16(af[kk], bfr, acc, 0, 0, 0);
    }
    int s = s0 + lo;
    #pragma unroll
    for (int r = 0; r < 4; ++r){
      int o = o0 + hi*4 + r;
      float val = acc[r] + qkvb[o];
      if (o < 128){
        int h = o >> 5, d = o & 31;
        qT[(((size_t)(b*NH + h))*S_TOT + s)*DH + d] = f2bf(val * SC);
      } else if (o < 256){
        int o2 = o - 128, h = o2 >> 5, d = o2 & 31;
        kv[(((size_t)(b*NH + h)*128 + (s >> 5)) << 11) + ((s & 31) << 5) + d] = f2bf(val);
      } else {
        int o3 = o - 256, h = o3 >> 5, d = o3 & 31;
        int pos = s & 31;
        int hi2 = (pos & 15) >> 2;
        int j2  = (pos & 3) + ((pos & 16) ? 4 : 0);
        kv[(((size_t)(b*NH + h)*128 + (s >> 5)) << 11) + 1024 + (d << 5) + hi2*8 + j2] = f2bf(val);
      }
    }
  }
}

// ---------------- kernel 5: flash attention, split-KV=8, 8-wave blocks, global_load_lds ----------------
// 512 threads = 8 waves x 32 queries; each wave stages 1KB (one g2l16) of the shared 8KB group.
__global__ void __launch_bounds__(512) k_attn(const unsigned short* __restrict__ qT,
                                              const unsigned short* __restrict__ kv,
                                              unsigned short* __restrict__ po,
                                              float* __restrict__ ls){
  __shared__ __align__(16) unsigned short smem[8192];   // 16 KB: 2 bufs x 2 tiles x 2048
  int lane = threadIdx.x & 63;
  int wid = threadIdx.x >> 6;          // 0..7
  int lo = lane & 15, hi = lane >> 4;
  int bh = blockIdx.x & 7;             // x%8 == head -> one head per XCD
  int sp = blockIdx.x >> 3;            // split 0..7
  int sw = blockIdx.y * 256 + wid * 32;
  int tb = sp * 16;                    // 16 tiles of 32 keys = 512 keys per split
  const unsigned short* qh = qT + (size_t)bh * S_TOT * DH;
  const unsigned short* kvbase = kv + (((size_t)bh*128 + tb) << 11);

  s16x8 qf0 = *(const s16x8*)(qh + (size_t)(sw + lo)*DH + hi*8);
  s16x8 qf1 = *(const s16x8*)(qh + (size_t)(sw + 16 + lo)*DH + hi*8);
  const f32x4 z = {0.f,0.f,0.f,0.f};
  f32x4 acc00 = z, acc01 = z, acc10 = z, acc11 = z, accL0 = z, accL1 = z;
  s16x8 onesf;
  #pragma unroll
  for (int i = 0; i < 8; ++i) onesf[i] = (short)0x3F80; // bf16 1.0

  auto compute = [&](const s16x8& kf0, const s16x8& kf1, const s16x8& vf0, const s16x8& vf1){
    __builtin_amdgcn_s_setprio(1);
    f32x4 p0 = __builtin_amdgcn_mfma_f32_16x16x32_bf16(kf0, qf0, z, 0, 0, 0);
    f32x4 p1 = __builtin_amdgcn_mfma_f32_16x16x32_bf16(kf1, qf0, z, 0, 0, 0);
    f32x4 r0 = __builtin_amdgcn_mfma_f32_16x16x32_bf16(kf0, qf1, z, 0, 0, 0);
    f32x4 r1 = __builtin_amdgcn_mfma_f32_16x16x32_bf16(kf1, qf1, z, 0, 0, 0);
    #pragma unroll
    for (int r = 0; r < 4; ++r){
      p0[r] = __builtin_amdgcn_exp2f(p0[r]);
      p1[r] = __builtin_amdgcn_exp2f(p1[r]);
      r0[r] = __builtin_amdgcn_exp2f(r0[r]);
      r1[r] = __builtin_amdgcn_exp2f(r1[r]);
    }
    union { unsigned u[4]; s16x8 v; } pa0, pa1;
    pa0.u[0] = cvtpk(p0[0],p0[1]); pa0.u[1] = cvtpk(p0[2],p0[3]);
    pa0.u[2] = cvtpk(p1[0],p1[1]); pa0.u[3] = cvtpk(p1[2],p1[3]);
    pa1.u[0] = cvtpk(r0[0],r0[1]); pa1.u[1] = cvtpk(r0[2],r0[3]);
    pa1.u[2] = cvtpk(r1[0],r1[1]); pa1.u[3] = cvtpk(r1[2],r1[3]);
    acc00 = __builtin_amdgcn_mfma_f32_16x16x32_bf16(pa0.v, vf0, acc00, 0, 0, 0);
    acc01 = __builtin_amdgcn_mfma_f32_16x16x32_bf16(pa0.v, vf1, acc01, 0, 0, 0);
    acc10 = __builtin_amdgcn_mfma_f32_16x16x32_bf16(pa1.v, vf0, acc10, 0, 0, 0);
    acc11 = __builtin_amdgcn_mfma_f32_16x16x32_bf16(pa1.v, vf1, acc11, 0, 0, 0);
    accL0 = __builtin_amdgcn_mfma_f32_16x16x32_bf16(pa0.v, onesf, accL0, 0, 0, 0);
    accL1 = __builtin_amdgcn_mfma_f32_16x16x32_bf16(pa1.v, onesf, accL1, 0, 0, 0);
    __builtin_amdgcn_s_setprio(0);
  };

  // prologue: async-stage group 0 into buf 0 (each wave: 1KB = one 16B/lane op)
  g2l16(kvbase + wid*512 + lane*8, smem + wid*512);
  __syncthreads();

  int buf = 0;
  for (int grp = 0; grp < 8; ++grp){
    if (grp < 7){                              // stage next group (skip redundant last)
      g2l16(kvbase + (grp + 1)*4096 + wid*512 + lane*8,
            smem + (buf^1)*4096 + wid*512);
    }
    const unsigned short* lb = smem + buf*4096 + (lo << 5) + hi*8;
    #pragma unroll
    for (int t = 0; t < 2; ++t){
      const unsigned short* tl = lb + t*2048;
      s16x8 kf0 = *(const s16x8*)(tl);
      s16x8 kf1 = *(const s16x8*)(tl + 512);
      s16x8 vf0 = *(const s16x8*)(tl + 1024);
      s16x8 vf1 = *(const s16x8*)(tl + 1536);
      compute(kf0, kf1, vf0, vf1);
    }
    __syncthreads();                           // drains vmcnt(0): staged group visible
    buf ^= 1;
  }

  unsigned short* pob = po + (size_t)(bh*8 + sp) * S_TOT * DH;
  float* lsb = ls + (size_t)(bh*8 + sp) * S_TOT;
  #pragma unroll
  for (int r = 0; r < 4; ++r){
    int s0r = sw + hi*4 + r;
    pob[(size_t)s0r*DH + lo]      = f2bf(acc00[r]);
    pob[(size_t)s0r*DH + lo + 16] = f2bf(acc01[r]);
    int s1r = sw + 16 + hi*4 + r;
    pob[(size_t)s1r*DH + lo]      = f2bf(acc10[r]);
    pob[(size_t)s1r*DH + lo + 16] = f2bf(acc11[r]);
  }
  if (lo == 0){
    #pragma unroll
    for (int r = 0; r < 4; ++r){
      lsb[sw + hi*4 + r]      = accL0[r];
      lsb[sw + 16 + hi*4 + r] = accL1[r];
    }
  }
}

// ---------------- kernel 5b: combine split-KV partials (bf16) -> aoT bf16 ----------------
__global__ void k_comb(const unsigned short* __restrict__ po, const float* __restrict__ ls,
                       unsigned short* __restrict__ aoT){
  int t = blockIdx.x * 256 + threadIdx.x;    // 262144 threads, 4 outputs each
  int d4 = (t & 7) * 4;
  int s  = (t >> 3) & 4095;
  int bh = t >> 15;
  float l = 0.f;
  float4 v = {0.f,0.f,0.f,0.f};
  #pragma unroll
  for (int sp = 0; sp < 8; ++sp){
    size_t base = (size_t)(bh*8 + sp) * S_TOT + s;
    l += ls[base];
    ushort4 pv = *(const ushort4*)(po + base*DH + d4);
    v.x += bf2f(pv.x); v.y += bf2f(pv.y); v.z += bf2f(pv.z); v.w += bf2f(pv.w);
  }
  float inv = 1.f / l;
  ushort4 o;
  o.x = f2bf(v.x * inv); o.y = f2bf(v.y * inv);
  o.z = f2bf(v.z * inv); o.w = f2bf(v.w * inv);
  *(ushort4*)(aoT + ((size_t)(bh*4096 + s))*DH + d4) = o;
}

// ---------------- kernel 6: proj GEMM + bias + residual (32-s tiles, 512 blocks) ----------------
__global__ void k_proj(const unsigned short* __restrict__ aoT, const unsigned short* __restrict__ wp,
                       const float* __restrict__ pb, const float* __restrict__ x,
                       float* __restrict__ out){
  int lane = threadIdx.x & 63, wid = threadIdx.x >> 6;
  int lo = lane & 15, hi = lane >> 4;
  int b  = blockIdx.z;
  int o0 = blockIdx.y * 64 + wid * 16;
  int sb = blockIdx.x * 32;
  s16x8 af[4];
  #pragma unroll
  for (int kk = 0; kk < 4; ++kk)
    af[kk] = *(const s16x8*)(wp + (size_t)(o0+lo)*CH + kk*32 + hi*8);
  #pragma unroll
  for (int st = 0; st < 2; ++st){
    int s0 = sb + st*16;
    f32x4 acc = {0.f,0.f,0.f,0.f};
    #pragma unroll
    for (int kk = 0; kk < 4; ++kk){
      s16x8 bfr = *(const s16x8*)(aoT + (((size_t)(b*NH + kk))*S_TOT + s0 + lo)*DH + hi*8);
      acc = __builtin_amdgcn_mfma_f32_16x16x32_bf16(af[kk], bfr, acc, 0, 0, 0);
    }
    #pragma unroll
    for (int r = 0; r < 4; ++r){
      int o = o0 + hi*4 + r;
      size_t idx = ((size_t)(b*CH + o))*S_TOT + s0 + lo;
      out[idx] = acc[r] + pb[o] + x[idx];
    }
  }
}

extern "C" void kernel_launch(void* const* d_in, const int* in_sizes, int n_in,
                              void* d_out, int out_size, void* d_ws, size_t ws_size,
                              hipStream_t stream){
  const float* x     = (const float*)d_in[0];
  const float* nw    = (const float*)d_in[1];
  const float* nb    = (const float*)d_in[2];
  const float* qkvw  = (const float*)d_in[3];
  const float* qkvb  = (const float*)d_in[4];
  const float* projw = (const float*)d_in[5];
  const float* projb = (const float*)d_in[6];
  float* out = (float*)d_out;
  char* ws = (char*)d_ws;
  const size_t MB = 1048576;
  unsigned short* qT  = (unsigned short*)(ws);            // 2MB
  unsigned short* kv  = (unsigned short*)(ws + 2*MB);     // 4MB (K+V interleaved per tile)
  unsigned short* aoT = (unsigned short*)(ws + 6*MB);     // 2MB
  unsigned short* wq  = (unsigned short*)(ws + 8*MB);           // 96KB
  unsigned short* wp  = (unsigned short*)(ws + 8*MB + 131072);  // 32KB
  float* stats        = (float*)(ws + 8*MB + 196608);           // 512B
  float* ls           = (float*)(ws + 8*MB + 262144);           // 1MB (64*4096*4B)
  unsigned short* hT  = (unsigned short*)(ws + 10*MB);    // 2MB
  unsigned short* po  = (unsigned short*)(ws + 12*MB);    // 16MB bf16 partials (total 28MB)

  hipLaunchKernelGGL(k_pre,     dim3(320),       dim3(256), 0, stream, x, stats, qkvw, projw, wq, wp);
  hipLaunchKernelGGL(k_gnapply, dim3(256),       dim3(256), 0, stream, x, stats, nw, nb, hT);
  hipLaunchKernelGGL(k_qkv,     dim3(64, 6, 2),  dim3(256), 0, stream, hT, wq, qkvb, qT, kv);
  hipLaunchKernelGGL(k_attn,    dim3(64, 16),    dim3(512), 0, stream, qT, kv, po, ls);
  hipLaunchKernelGGL(k_comb,    dim3(1024),      dim3(256), 0, stream, po, ls, aoT);
  hipLaunchKernelGGL(k_proj,    dim3(128, 2, 2), dim3(256), 0, stream, aoT, wp, projb, x, out);
}